// Round 9
// baseline (33.118 us; speedup 1.0000x reference)
//
#include <hip/hip_runtime.h>
#include <hip/hip_bf16.h>
#include <math.h>

#define Bn   16
#define T1n  256
#define T2n  256
#define Dn   256
#define MPn  32

typedef __attribute__((ext_vector_type(8))) short short8;
typedef __attribute__((ext_vector_type(4))) float f32x4;

__device__ inline short f2b(float f) {
  __hip_bfloat16 h = __float2bfloat16(f);
  return __builtin_bit_cast(short, h);
}
__device__ inline float b2f(short s) {
  unsigned int u = ((unsigned int)(unsigned short)s) << 16;
  return __builtin_bit_cast(float, u);
}
__device__ inline float max4(f32x4 a) {
  return fmaxf(fmaxf(a.x, a.y), fmaxf(a.z, a.w));
}

// ---- pre-pass: pack lt/rt into MFMA-fragment order, bf16 ----
// ltp[b][ic(16)][kk(8)][lane(64)][8] : lane l -> lt[b][ic*16 + (l&15)][kk*32 + (l>>4)*8 + e]
// rtp[b][jb(8)][sub(2)][kk(8)][lane(64)][8] : lane l -> rt[b][jb*32+sub*16+(l&15)][kk*32+(l>>4)*8+e]
// Main-kernel fragment loads become ONE contiguous 1KB wave-load each.
__global__ __launch_bounds__(512, 4)
void pack_kernel(const float* __restrict__ lt, const float* __restrict__ rt,
                 short* __restrict__ ltp, short* __restrict__ rtp) {
  const int idx = blockIdx.x * 512 + threadIdx.x;   // 0..262143
  const bool isR = idx >= 131072;                   // blocks 0..255: lt, 256..511: rt
  const int id = isR ? (idx - 131072) : idx;
  const int lane = id & 63;
  const int kk   = (id >> 6) & 7;
  const int bl   = lane & 15;
  const int hl   = lane >> 4;
  const int d0   = kk * 32 + hl * 8;

  const float* src;
  short* dst;
  if (!isR) {
    const int ic = (id >> 9) & 15;
    const int b  = id >> 13;
    src = lt + (((size_t)b * T1n + ic * 16 + bl) * Dn + d0);
    dst = ltp + (size_t)id * 8;
  } else {
    const int sub = (id >> 9) & 1;
    const int jb  = (id >> 10) & 7;
    const int b   = id >> 13;
    src = rt + (((size_t)b * T2n + jb * 32 + sub * 16 + bl) * Dn + d0);
    dst = rtp + (size_t)id * 8;
  }
  const f32x4* s = reinterpret_cast<const f32x4*>(src);
  f32x4 f0 = s[0], f1 = s[1];
  short8 v;
  v[0] = f2b(f0.x); v[1] = f2b(f0.y); v[2] = f2b(f0.z); v[3] = f2b(f0.w);
  v[4] = f2b(f1.x); v[5] = f2b(f1.y); v[6] = f2b(f1.z); v[7] = f2b(f1.w);
  *reinterpret_cast<short8*>(dst) = v;
}

// ---- main: ZERO LDS, zero barriers. 1024 blocks = b(16) x jb(8: 32j) x mg(8: 4m).
// 4 waves; wave -> own m; all waves share the identical A-fragment stream (L1 dedup).
__global__ __launch_bounds__(256, 4)
void mp_match_kernel(const short* __restrict__ ltp,
                     const short* __restrict__ rtp,
                     const float* __restrict__ kern,
                     float* __restrict__ out) {
  const int bid = blockIdx.x;          // 1024 blocks
  const int xcd = bid & 7;             // b = xcd or 8+xcd -> per-XCD L2 residency
  const int idx = bid >> 3;            // 0..127
  const int b   = ((idx >> 6) << 3) | xcd;
  const int rem = idx & 63;
  const int jb  = rem & 7;             // 8 j-strips of 32
  const int mg  = rem >> 3;            // 8 m-groups of 4

  const int tid  = threadIdx.x;        // 0..255
  const int lane = tid & 63;
  const int w    = tid >> 6;           // wave -> its own m
  const int m    = mg * 4 + w;
  const int bl   = lane & 15;
  const int hl   = lane >> 4;

  // ---- B fragments: coalesced from rtp, scaled by k[m] in regs ----
  const short* rbase = rtp + ((size_t)(b * 8 + jb) * 2) * 8 * 64 * 8;
  const float* kbase = kern + (size_t)m * Dn;
  short8 bsc[2][8];                    // 64 VGPR
  #pragma unroll
  for (int kk = 0; kk < 8; ++kk) {
    const f32x4* kp = reinterpret_cast<const f32x4*>(kbase + (kk * 4 + hl) * 8);
    f32x4 k0 = kp[0], k1 = kp[1];
    #pragma unroll
    for (int sub = 0; sub < 2; ++sub) {
      short8 r = *reinterpret_cast<const short8*>(
          rbase + ((size_t)(sub * 8 + kk) * 64 + lane) * 8);
      short8 v;
      v[0] = f2b(b2f(r[0]) * k0.x); v[1] = f2b(b2f(r[1]) * k0.y);
      v[2] = f2b(b2f(r[2]) * k0.z); v[3] = f2b(b2f(r[3]) * k0.w);
      v[4] = f2b(b2f(r[4]) * k1.x); v[5] = f2b(b2f(r[5]) * k1.y);
      v[6] = f2b(b2f(r[6]) * k1.z); v[7] = f2b(b2f(r[7]) * k1.w);
      bsc[sub][kk] = v;
    }
  }

  float jmax0 = -1e30f, jmax1 = -1e30f;

  // ---- 16 chunks of 16 i-rows; A-frags = contiguous 1KB wave-loads ----
  const short* abase = ltp + (size_t)b * 16 * 8 * 64 * 8;
  #pragma unroll 1
  for (int ic = 0; ic < 16; ++ic) {
    short8 A[8];
    #pragma unroll
    for (int kk = 0; kk < 8; ++kk)
      A[kk] = *reinterpret_cast<const short8*>(
          abase + ((size_t)(ic * 8 + kk) * 64 + lane) * 8);
    f32x4 a0 = {0.f, 0.f, 0.f, 0.f};
    f32x4 a1 = {0.f, 0.f, 0.f, 0.f};
    #pragma unroll
    for (int kk = 0; kk < 8; ++kk) {
      a0 = __builtin_amdgcn_mfma_f32_16x16x32_bf16(A[kk], bsc[0][kk], a0, 0, 0, 0);
      a1 = __builtin_amdgcn_mfma_f32_16x16x32_bf16(A[kk], bsc[1][kk], a1, 0, 0, 0);
    }
    jmax0 = fmaxf(jmax0, max4(a0));
    jmax1 = fmaxf(jmax1, max4(a1));
  }

  // ---- cross-lane col-max over the 4 row-groups, tanh, store ----
  jmax0 = fmaxf(jmax0, __shfl_xor(jmax0, 16));
  jmax0 = fmaxf(jmax0, __shfl_xor(jmax0, 32));
  jmax1 = fmaxf(jmax1, __shfl_xor(jmax1, 16));
  jmax1 = fmaxf(jmax1, __shfl_xor(jmax1, 32));
  if (hl < 2) {
    float v = hl ? jmax1 : jmax0;
    int j = jb * 32 + hl * 16 + bl;
    out[((size_t)b * T2n + j) * MPn + m] = tanhf(v);
  }
}

extern "C" void kernel_launch(void* const* d_in, const int* in_sizes, int n_in,
                              void* d_out, int out_size, void* d_ws, size_t ws_size,
                              hipStream_t stream) {
  const float* lt   = (const float*)d_in[0];
  const float* rt   = (const float*)d_in[1];
  const float* kern = (const float*)d_in[2];
  float* out = (float*)d_out;

  short* ltp = (short*)d_ws;                         // 2 MB, fragment-ordered lt
  short* rtp = ltp + (size_t)131072 * 8;             // 2 MB, fragment-ordered rt

  pack_kernel<<<512, 512, 0, stream>>>(lt, rt, ltp, rtp);
  mp_match_kernel<<<1024, 256, 0, stream>>>(ltp, rtp, kern, out);
}